// Round 12
// baseline (161.686 us; speedup 1.0000x reference)
//
#include <hip/hip_runtime.h>

typedef __attribute__((ext_vector_type(4))) float f32x4;
typedef __attribute__((ext_vector_type(8))) short bf16x8;

#define OPLANE 2916     // 54*54
#define NN 23328        // 8*54*54
#define KDIM 1152       // 128*9
#define PLANE 3136      // 56*56
#define LDP 72          // BK=64 LDS row (shorts): 144B stride -> 2-way alias (free)
#define LDP2 136        // BK=128 LDS row (shorts): 272B stride -> 2-way alias (free)

__device__ __forceinline__ unsigned short f2bf(float f) {
    unsigned u = __builtin_bit_cast(unsigned, f);
    u += 0x7fffu + ((u >> 16) & 1u);
    return (unsigned short)(u >> 16);
}
__device__ __forceinline__ float bflo(unsigned u) {   // low bf16 of dword -> f32
    return __builtin_bit_cast(float, u << 16);
}
__device__ __forceinline__ float bfhi(unsigned u) {   // high bf16 of dword -> f32
    return __builtin_bit_cast(float, u & 0xffff0000u);
}

// ---- k_pre: fused {weights->bf16 K-permute} + {x NCHW fp32 -> NHWC bf16} ----
__global__ __launch_bounds__(256) void k_pre(const float* __restrict__ x,
                                             const float* __restrict__ w0,
                                             const float* __restrict__ lw,
                                             unsigned short* __restrict__ xnh,
                                             unsigned short* __restrict__ b1t,
                                             unsigned short* __restrict__ b2t) {
    __shared__ unsigned short lds[56 * 132];
    if (blockIdx.x < 1728) {
        int idx = blockIdx.x * 256 + threadIdx.x;   // 442368 = 147456 + 294912
        if (idx < 147456) {
            int r = idx / KDIM, k = idx - r * KDIM;
            int ij = k >> 7, ic = k & 127;
            b1t[idx] = f2bf(w0[r * KDIM + ic * 9 + ij]);
        } else {
            int j = idx - 147456;
            int r = j / KDIM, k = j - r * KDIM;
            int ij = k >> 7, ic = k & 127;
            b2t[j] = f2bf(lw[r * KDIM + ic * 9 + ij]);
        }
    } else {
        const int bid = blockIdx.x - 1728;
        const int y = bid % 56, b = bid / 56, tid = threadIdx.x;
        for (int i = tid; i < 7168; i += 256) {
            int ic = i / 56, xc = i - ic * 56;
            lds[xc * 132 + ic] = f2bf(x[(b * 128 + ic) * PLANE + y * 56 + xc]);
        }
        __syncthreads();
        for (int i = tid; i < 7168; i += 256) {
            int xc = i >> 7, ic = i & 127;
            xnh[(b * PLANE + y * 56 + xc) * 128 + ic] = lds[xc * 132 + ic];
        }
    }
}

// ---- gemm1 (fused im2col): h = relu(im2col(xnh) * b1t^T + b0), h stored BF16 ----
// BK=128 (9 stages, half the barrier-drains). XCD-chunked m-tiles (392 = 8 x 49).
// Grid-limited occupancy (1.53 blocks/CU) -> 52 KB LDS costs nothing here.
__global__ __launch_bounds__(512) void k_gemm1(const unsigned short* __restrict__ xnh,
                                               const unsigned short* __restrict__ Bt,
                                               const float* __restrict__ bias,
                                               unsigned short* __restrict__ h) {
    __shared__ unsigned short As[64 * LDP2];    // 17.4 KB
    __shared__ unsigned short Bs[128 * LDP2];   // 34.8 KB
    const int tid = threadIdx.x;
    const int lane = tid & 63, wid = tid >> 6;   // 8 waves
    const int wr = wid >> 2, wc = wid & 3;       // 2 m-halves x 4 n-quarters
    const int mt_id = (blockIdx.x & 7) * 49 + (blockIdx.x >> 3);  // chunked remap
    const int m0 = mt_id * 64;

    f32x4 acc[2][2];
    #pragma unroll
    for (int mt = 0; mt < 2; mt++)
        #pragma unroll
        for (int nt = 0; nt < 2; nt++) { acc[mt][nt][0]=0.f; acc[mt][nt][1]=0.f; acc[mt][nt][2]=0.f; acc[mt][nt][3]=0.f; }

    // A staging: row = sample (64), 8 threads/row, 16 shorts (2 uint4) each
    const int row = tid >> 3, q = tid & 7;
    const int p = m0 + row;
    const int b = p / PLANE; int rem = p - b * PLANE;
    const int y = rem / 56; const int xc = rem - y * 56;
    unsigned short* asw = &As[row * LDP2 + q * 16];
    // B staging: 128 rows, 4 threads/row, 32 shorts (4 uint4) each
    const int brow = tid >> 2, bq = tid & 3;
    const unsigned short* bg = Bt + brow * KDIM + bq * 32;
    unsigned short* bsw = &Bs[brow * LDP2 + bq * 32];
    const int lm = lane & 15, lq = lane >> 4;

    uint4 a0, a1, bv0, bv1, bv2, bv3;
    auto issue = [&](int ij) {
        const int di = ij / 3, dj = ij - di * 3;
        a0 = make_uint4(0u,0u,0u,0u); a1 = a0;
        bool valid = (y + di >= 1) && (y + di <= 56) && (xc + dj >= 1) && (xc + dj <= 56);
        if (valid) {
            const unsigned short* ap = xnh + (p + (di - 1) * 56 + (dj - 1)) * 128 + q * 16;
            a0 = *(const uint4*)ap;
            a1 = *(const uint4*)(ap + 8);
        }
        const unsigned short* bp = bg + ij * 128;
        bv0 = *(const uint4*)(bp + 0);
        bv1 = *(const uint4*)(bp + 8);
        bv2 = *(const uint4*)(bp + 16);
        bv3 = *(const uint4*)(bp + 24);
    };
    issue(0);

    #pragma unroll
    for (int it = 0; it < 9; it++) {
        __syncthreads();
        *(uint4*)(asw + 0) = a0;  *(uint4*)(asw + 8) = a1;
        *(uint4*)(bsw + 0)  = bv0; *(uint4*)(bsw + 8)  = bv1;
        *(uint4*)(bsw + 16) = bv2; *(uint4*)(bsw + 24) = bv3;
        __syncthreads();
        if (it < 8) issue(it + 1);
        #pragma unroll
        for (int kk = 0; kk < 128; kk += 32) {
            bf16x8 af[2], bf[2];
            #pragma unroll
            for (int mt = 0; mt < 2; mt++)
                af[mt] = *(const bf16x8*)&As[(wr * 32 + mt * 16 + lm) * LDP2 + kk + lq * 8];
            #pragma unroll
            for (int nt = 0; nt < 2; nt++)
                bf[nt] = *(const bf16x8*)&Bs[(wc * 32 + nt * 16 + lm) * LDP2 + kk + lq * 8];
            #pragma unroll
            for (int mt = 0; mt < 2; mt++)
                #pragma unroll
                for (int nt = 0; nt < 2; nt++)
                    acc[mt][nt] = __builtin_amdgcn_mfma_f32_16x16x32_bf16(af[mt], bf[nt], acc[mt][nt], 0, 0, 0);
        }
    }
    #pragma unroll
    for (int mt = 0; mt < 2; mt++) {
        int m = m0 + wr * 32 + mt * 16 + lq * 4;
        #pragma unroll
        for (int nt = 0; nt < 2; nt++) {
            int n = wc * 32 + nt * 16 + lm;
            float bb = bias[n];
            #pragma unroll
            for (int r = 0; r < 4; r++)
                h[(m + r) * 128 + n] = f2bf(fmaxf(acc[mt][nt][r] + bb, 0.f));
        }
    }
}

// ---- k_conv2f: conv2 (NHWC bf16 h, LDS fp32 weights) + theta epilogue, fused ----
// XCD-chunked: grid 1464 = 8 x 183 (6 idle).
__global__ __launch_bounds__(256) void k_conv2f(const unsigned short* __restrict__ h,
                                                const float* __restrict__ w1,
                                                const int* __restrict__ check,
                                                float* __restrict__ o_out,
                                                float* __restrict__ o_th,
                                                float* __restrict__ o_ax,
                                                float* __restrict__ o_ay,
                                                float* __restrict__ sxy) {
    __shared__ float wlds[6912];        // [r][ij*128+ic]
    __shared__ float red[16 * 6 * 17];  // [pt][r][c] stride-17
    __shared__ float vals[96];
    const int bid = (blockIdx.x & 7) * 183 + (blockIdx.x >> 3);   // chunked remap
    if (bid >= 1458) return;            // uniform early-out, before any barrier
    const int tid = threadIdx.x;
    for (int idx = tid; idx < 6912; idx += 256) {
        int r = idx / KDIM, k = idx - r * KDIM;
        int ij = k >> 7, ic = k & 127;
        wlds[idx] = w1[r * KDIM + ic * 9 + ij];
    }
    __syncthreads();
    const int pt = tid >> 4, c = tid & 15;
    const int p = bid * 16 + pt;
    int b = p / OPLANE; int rem = p - b * OPLANE; int oh = rem / 54; int ow = rem - oh * 54;
    const uint4* h4 = (const uint4*)h;          // 8 bf16 channels per uint4
    const float4* w4 = (const float4*)wlds;
    float acc[6] = {0.f, 0.f, 0.f, 0.f, 0.f, 0.f};
    const int base_sp = b * PLANE + oh * 56 + ow;
    #pragma unroll
    for (int i = 0; i < 3; i++) {
        #pragma unroll
        for (int j = 0; j < 3; j++) {
            int sp = base_sp + i * 56 + j;
            uint4 hu = h4[sp * 16 + c];         // ch c*8 .. c*8+7 (bf16 pairs)
            float f0 = bflo(hu.x), f1 = bfhi(hu.x);
            float f2 = bflo(hu.y), f3 = bfhi(hu.y);
            float f4 = bflo(hu.z), f5 = bfhi(hu.z);
            float f6 = bflo(hu.w), f7 = bfhi(hu.w);
            int ij = i * 3 + j;
            #pragma unroll
            for (int r = 0; r < 6; r++) {
                float4 wa = w4[r * 288 + ij * 32 + c * 2];
                float4 wb = w4[r * 288 + ij * 32 + c * 2 + 1];
                acc[r] += f0 * wa.x + f1 * wa.y + f2 * wa.z + f3 * wa.w
                        + f4 * wb.x + f5 * wb.y + f6 * wb.z + f7 * wb.w;
            }
        }
    }
    #pragma unroll
    for (int r = 0; r < 6; r++) red[(pt * 6 + r) * 17 + c] = acc[r];
    __syncthreads();
    if (tid < 96) {
        const float* rp = &red[tid * 17];
        float s = 0.f;
        #pragma unroll
        for (int e = 0; e < 16; e++) s += rp[e];
        vals[tid] = s;
    }
    __syncthreads();
    if (tid < 16) {
        int p2 = bid * 16 + tid;
        int b2 = p2 / OPLANE; int r2 = p2 - b2 * OPLANE; int oh2 = r2 / 54; int ow2 = r2 - oh2 * 54;
        float val[6];
        float s = 1.0f - (float)check[0];
        const float id6[6] = {1.f, 0.f, 0.f, 0.f, 1.f, 0.f};
        #pragma unroll
        for (int r = 0; r < 6; r++) val[r] = vals[tid * 6 + r] * s + id6[r];
        int n = (b2 * 54 + ow2) * 54 + oh2;
        #pragma unroll
        for (int r = 0; r < 6; r++) {
            o_out[((b2 * 6 + r) * 54 + oh2) * 54 + ow2] = val[r];
            o_th[n * 6 + r] = id6[r] - val[r];
        }
        const float bse[3] = {-2.f / 3.f, 0.f, 2.f / 3.f};
        #pragma unroll
        for (int i = 0; i < 3; i++)
            #pragma unroll
            for (int j = 0; j < 3; j++) {
                float gx = bse[j] * val[0] + bse[i] * val[1] + val[2];
                float gy = bse[j] * val[3] + bse[i] * val[4] + val[5];
                float ax = (gx + 1.f + (float)ow2) * (2.f / 55.f) - 1.f;
                float ay = (gy + 1.f + (float)oh2) * (2.f / 55.f) - 1.f;
                int ij = i * 3 + j;
                o_ax[n * 9 + ij] = ax;
                o_ay[n * 9 + ij] = ay;
                sxy[(n * 9 + ij) * 2 + 0] = (ax + 1.f) * 28.f - 0.5f;
                sxy[(n * 9 + ij) * 2 + 1] = (ay + 1.f) * 28.f - 0.5f;
            }
    }
}

// ---- k_sgemm: proven 64s x 128o + XCD chunked swizzle + cvt_pk pack ----
__global__ __launch_bounds__(256) void k_sgemm(const unsigned short* __restrict__ xnh,
                                               const unsigned short* __restrict__ Wt,
                                               const float* __restrict__ bias,
                                               const float* __restrict__ sxy,
                                               float* __restrict__ score) {
    __shared__ unsigned short Ss[64 * LDP];    // samples (A-tile, gathered)
    __shared__ unsigned short Ws[128 * LDP];   // o-rows
    const int i = blockIdx.x;
    const int xcd = i & 7, j = i >> 3;         // j in [0,92)
    const int pp = xcd * 46 + (j >> 1);        // 46 contiguous s-tiles per XCD
    const int m8 = j & 1;                      // o-half (pair member, same XCD)
    if (pp >= 365) return;                     // uniform per-block
    const int o0 = m8 * 128;
    const int s0 = pp * 64;
    const int tid = threadIdx.x;
    const int lane = tid & 63, wid = tid >> 6;
    const int wr = wid >> 1, wc = wid & 1;

    f32x4 acc[4][2];
    #pragma unroll
    for (int mt = 0; mt < 4; mt++)
        #pragma unroll
        for (int nt = 0; nt < 2; nt++) { acc[mt][nt][0]=0.f; acc[mt][nt][1]=0.f; acc[mt][nt][2]=0.f; acc[mt][nt][3]=0.f; }

    // gather assignment: row = sample (64), q = ic-sixteenth (4)
    const int row = tid >> 2, q = tid & 3;
    const int mp = min(s0 + row, NN - 1);           // score-linear sample id
    const int b = mp / OPLANE; const int rr = mp - b * OPLANE;
    const int ho = rr / 54, wo = rr - (rr / 54) * 54;
    const int n = (b * 54 + wo) * 54 + ho;          // theta-order id (sxy index)
    const int xbase = b * PLANE;
    unsigned short* ssw = &Ss[row * LDP + q * 16];
    // weight staging: wrow = o-row (128), wq = half (2), 4 uint4 per thread
    const int wrow = tid >> 1, wq = tid & 1;
    const unsigned short* wg = Wt + (o0 + wrow) * KDIM + wq * 32;
    unsigned short* wsw = &Ws[wrow * LDP + wq * 32];
    const int lm = lane & 15, lq = lane >> 4;

    // hoist all 9 sample coordinates out of the K-loop
    float2 sc[9];
    {
        const float* spp = sxy + n * 18;
        #pragma unroll
        for (int ij = 0; ij < 9; ij++) sc[ij] = *(const float2*)(spp + ij * 2);
    }

    int off0 = 0, off1 = 0, off2 = 0, off3 = 0;
    float wt0 = 0.f, wt1 = 0.f, wt2 = 0.f, wt3 = 0.f;
    auto mkoff = [&](int ij) {
        float sx = sc[ij].x, sy = sc[ij].y;
        float x0f = floorf(sx), y0f = floorf(sy);
        float wx = sx - x0f, wy = sy - y0f;
        int x0 = (int)x0f, y0 = (int)y0f;
        int x1 = x0 + 1, y1 = y0 + 1;
        float vx0 = (x0 >= 0 && x0 < 56) ? 1.f : 0.f;
        float vx1 = (x1 >= 0 && x1 < 56) ? 1.f : 0.f;
        float vy0 = (y0 >= 0 && y0 < 56) ? 1.f : 0.f;
        float vy1 = (y1 >= 0 && y1 < 56) ? 1.f : 0.f;
        int xc0 = min(max(x0, 0), 55), xc1 = min(max(x1, 0), 55);
        int yc0 = min(max(y0, 0), 55), yc1 = min(max(y1, 0), 55);
        off0 = (xbase + yc0 * 56 + xc0) << 7;
        off1 = (xbase + yc0 * 56 + xc1) << 7;
        off2 = (xbase + yc1 * 56 + xc0) << 7;
        off3 = (xbase + yc1 * 56 + xc1) << 7;
        wt0 = vy0 * vx0 * (1.f - wx) * (1.f - wy);
        wt1 = vy0 * vx1 * wx * (1.f - wy);
        wt2 = vy1 * vx0 * (1.f - wx) * wy;
        wt3 = vy1 * vx1 * wx * wy;
    };

    uint4 p0a, p0b, p1a, p1b, p2a, p2b, p3a, p3b;
    uint4 w0v, w1v, w2v, w3v;
    auto issue = [&](int it) {
        const int co = ((it & 1) << 6) + q * 16;
        p0a = *(const uint4*)(xnh + off0 + co);
        p0b = *(const uint4*)(xnh + off0 + co + 8);
        p1a = *(const uint4*)(xnh + off1 + co);
        p1b = *(const uint4*)(xnh + off1 + co + 8);
        p2a = *(const uint4*)(xnh + off2 + co);
        p2b = *(const uint4*)(xnh + off2 + co + 8);
        p3a = *(const uint4*)(xnh + off3 + co);
        p3b = *(const uint4*)(xnh + off3 + co + 8);
        w0v = *(const uint4*)(wg + it * 64);
        w1v = *(const uint4*)(wg + it * 64 + 8);
        w2v = *(const uint4*)(wg + it * 64 + 16);
        w3v = *(const uint4*)(wg + it * 64 + 24);
    };

    mkoff(0);
    issue(0);

    #pragma unroll
    for (int it = 0; it < 18; it++) {
        // blend 16 lanes (plain C, compiler-scheduled); pack via v_cvt_pk_bf16_f32
        unsigned dw[8];
        const unsigned* d0 = (const unsigned*)&p0a;
        const unsigned* d1 = (const unsigned*)&p1a;
        const unsigned* d2 = (const unsigned*)&p2a;
        const unsigned* d3 = (const unsigned*)&p3a;
        const unsigned* e0 = (const unsigned*)&p0b;
        const unsigned* e1 = (const unsigned*)&p1b;
        const unsigned* e2 = (const unsigned*)&p2b;
        const unsigned* e3 = (const unsigned*)&p3b;
        #pragma unroll
        for (int d = 0; d < 8; d++) {
            unsigned u0 = (d < 4) ? d0[d] : e0[d - 4];
            unsigned u1 = (d < 4) ? d1[d] : e1[d - 4];
            unsigned u2 = (d < 4) ? d2[d] : e2[d - 4];
            unsigned u3 = (d < 4) ? d3[d] : e3[d - 4];
            float lo = wt0 * bflo(u0) + wt1 * bflo(u1) + wt2 * bflo(u2) + wt3 * bflo(u3);
            float hi = wt0 * bfhi(u0) + wt1 * bfhi(u1) + wt2 * bfhi(u2) + wt3 * bfhi(u3);
            unsigned pk;
            asm("v_cvt_pk_bf16_f32 %0, %1, %2" : "=v"(pk) : "v"(lo), "v"(hi));
            dw[d] = pk;
        }
        __syncthreads();                      // prev MFMA reads of LDS done
        *(uint4*)(ssw + 0) = *(uint4*)&dw[0];
        *(uint4*)(ssw + 8) = *(uint4*)&dw[4];
        *(uint4*)(wsw + 0)  = w0v;
        *(uint4*)(wsw + 8)  = w1v;
        *(uint4*)(wsw + 16) = w2v;
        *(uint4*)(wsw + 24) = w3v;
        __syncthreads();
        if (it < 17) {                        // prefetch next stage
            if (((it + 1) & 1) == 0) mkoff((it + 1) >> 1);
            issue(it + 1);
        }
        #pragma unroll
        for (int kk = 0; kk < 64; kk += 32) {
            bf16x8 wf[4], sf[2];
            #pragma unroll
            for (int mt = 0; mt < 4; mt++)
                wf[mt] = *(const bf16x8*)&Ws[(wr * 64 + mt * 16 + lm) * LDP + kk + lq * 8];
            #pragma unroll
            for (int nt = 0; nt < 2; nt++)
                sf[nt] = *(const bf16x8*)&Ss[(wc * 32 + nt * 16 + lm) * LDP + kk + lq * 8];
            #pragma unroll
            for (int mt = 0; mt < 4; mt++)
                #pragma unroll
                for (int nt = 0; nt < 2; nt++)
                    acc[mt][nt] = __builtin_amdgcn_mfma_f32_16x16x32_bf16(wf[mt], sf[nt], acc[mt][nt], 0, 0, 0);
        }
    }
    #pragma unroll
    for (int mt = 0; mt < 4; mt++) {
        #pragma unroll
        for (int r = 0; r < 4; r++) {
            int o = o0 + wr * 64 + mt * 16 + lq * 4 + r;
            float bb = bias[o];
            #pragma unroll
            for (int nt = 0; nt < 2; nt++) {
                int s = s0 + wc * 32 + nt * 16 + lm;
                if (s < NN) {
                    int sb = s / OPLANE;
                    int soff = s - sb * OPLANE;
                    score[(sb * 256 + o) * OPLANE + soff] = acc[mt][nt][r] + bb;
                }
            }
        }
    }
}

extern "C" void kernel_launch(void* const* d_in, const int* in_sizes, int n_in,
                              void* d_out, int out_size, void* d_ws, size_t ws_size,
                              hipStream_t stream) {
    const float* x  = (const float*)d_in[0];
    const float* w0 = (const float*)d_in[1];
    const float* b0 = (const float*)d_in[2];
    const float* w1 = (const float*)d_in[3];
    const float* lw = (const float*)d_in[4];
    const float* lb = (const float*)d_in[5];
    const int* check = (const int*)d_in[6];

    float* out   = (float*)d_out;
    float* score = out;                    // 8*256*54*54 = 5,971,968
    float* o_th  = out + 5971968;          // 139,968
    float* o_out = out + 6111936;          // 139,968
    float* o_ax  = out + 6251904;          // 209,952
    float* o_ay  = out + 6461856;          // 209,952

    char* wsb = (char*)d_ws;
    unsigned short* h   = (unsigned short*)wsb;                  //   6,422,528 B (bf16)
    unsigned short* xnh = (unsigned short*)(wsb + 12845056);     //   6,422,528 B
    unsigned short* b1t = (unsigned short*)(wsb + 19267584);     //     294,912 B
    unsigned short* b2t = (unsigned short*)(wsb + 19562496);     //     589,824 B
    float* sxy = (float*)(wsb + 20152320);                       //   1,679,616 B -> 21.8 MB total

    k_pre<<<2176, 256, 0, stream>>>(x, w0, lw, xnh, b1t, b2t);
    k_gemm1<<<392, 512, 0, stream>>>(xnh, b1t, b0, h);
    k_conv2f<<<1464, 256, 0, stream>>>(h, w1, check, o_out, o_th, o_ax, o_ay, sxy);
    k_sgemm<<<736, 256, 0, stream>>>(xnh, b2t, lb, sxy, score);
}

// Round 13
// 160.253 us; speedup vs baseline: 1.0089x; 1.0089x over previous
//
#include <hip/hip_runtime.h>

typedef __attribute__((ext_vector_type(4))) float f32x4;
typedef __attribute__((ext_vector_type(8))) short bf16x8;

#define OPLANE 2916     // 54*54
#define NN 23328        // 8*54*54
#define KDIM 1152       // 128*9
#define PLANE 3136      // 56*56
#define LDP 72          // LDS row (shorts): 144B stride -> 2-way alias (free)

__device__ __forceinline__ unsigned short f2bf(float f) {
    unsigned u = __builtin_bit_cast(unsigned, f);
    u += 0x7fffu + ((u >> 16) & 1u);
    return (unsigned short)(u >> 16);
}
__device__ __forceinline__ float bflo(unsigned u) {   // low bf16 of dword -> f32
    return __builtin_bit_cast(float, u << 16);
}
__device__ __forceinline__ float bfhi(unsigned u) {   // high bf16 of dword -> f32
    return __builtin_bit_cast(float, u & 0xffff0000u);
}

// ---- k_pre: fused {weights->bf16 K-permute} + {x NCHW fp32 -> NHWC bf16} ----
__global__ __launch_bounds__(256) void k_pre(const float* __restrict__ x,
                                             const float* __restrict__ w0,
                                             const float* __restrict__ lw,
                                             unsigned short* __restrict__ xnh,
                                             unsigned short* __restrict__ b1t,
                                             unsigned short* __restrict__ b2t) {
    __shared__ unsigned short lds[56 * 132];
    if (blockIdx.x < 1728) {
        int idx = blockIdx.x * 256 + threadIdx.x;   // 442368 = 147456 + 294912
        if (idx < 147456) {
            int r = idx / KDIM, k = idx - r * KDIM;
            int ij = k >> 7, ic = k & 127;
            b1t[idx] = f2bf(w0[r * KDIM + ic * 9 + ij]);
        } else {
            int j = idx - 147456;
            int r = j / KDIM, k = j - r * KDIM;
            int ij = k >> 7, ic = k & 127;
            b2t[j] = f2bf(lw[r * KDIM + ic * 9 + ij]);
        }
    } else {
        const int bid = blockIdx.x - 1728;
        const int y = bid % 56, b = bid / 56, tid = threadIdx.x;
        for (int i = tid; i < 7168; i += 256) {
            int ic = i / 56, xc = i - ic * 56;
            lds[xc * 132 + ic] = f2bf(x[(b * 128 + ic) * PLANE + y * 56 + xc]);
        }
        __syncthreads();
        for (int i = tid; i < 7168; i += 256) {
            int xc = i >> 7, ic = i & 127;
            xnh[(b * PLANE + y * 56 + xc) * 128 + ic] = lds[xc * 132 + ic];
        }
    }
}

// ---- gemm1 (fused im2col): h = relu(im2col(xnh) * b1t^T + b0), h stored BF16 ----
// BK=64, DOUBLE-BUFFERED LDS -> ONE barrier per stage (18 vs 36 drains).
// Grid-limited occupancy (1.53 blocks/CU); 55.3 KB LDS still allows 2/CU: free.
__global__ __launch_bounds__(512) void k_gemm1(const unsigned short* __restrict__ xnh,
                                               const unsigned short* __restrict__ Bt,
                                               const float* __restrict__ bias,
                                               unsigned short* __restrict__ h) {
    __shared__ unsigned short As[2][64 * LDP];
    __shared__ unsigned short Bs[2][128 * LDP];
    const int tid = threadIdx.x;
    const int lane = tid & 63, wid = tid >> 6;   // 8 waves
    const int wr = wid >> 2, wc = wid & 3;       // 2 m-halves x 4 n-quarters
    const int mt_id = (blockIdx.x & 7) * 49 + (blockIdx.x >> 3);  // chunked remap
    const int m0 = mt_id * 64;

    f32x4 acc[2][2];
    #pragma unroll
    for (int mt = 0; mt < 2; mt++)
        #pragma unroll
        for (int nt = 0; nt < 2; nt++) { acc[mt][nt][0]=0.f; acc[mt][nt][1]=0.f; acc[mt][nt][2]=0.f; acc[mt][nt][3]=0.f; }

    // A staging: row = sample (64), 8 threads/row, 8 shorts (1 uint4) each
    const int row = tid >> 3, q = tid & 7;
    const int p = m0 + row;
    const int b = p / PLANE; int rem = p - b * PLANE;
    const int y = rem / 56; const int xc = rem - y * 56;
    const int aswo = row * LDP + q * 8;
    // B staging: 128 rows, 4 threads/row, 16 shorts (2 uint4) each
    const int brow = tid >> 2, bq = tid & 3;
    const unsigned short* bg = Bt + brow * KDIM + bq * 16;
    const int bswo = brow * LDP + bq * 16;
    const int lm = lane & 15, lq = lane >> 4;

    uint4 a0, bv0, bv1;
    auto issue = [&](int it) {
        const int ij = it >> 1;
        const int di = ij / 3, dj = ij - di * 3;
        const int icb = (it & 1) << 6;
        a0 = make_uint4(0u,0u,0u,0u);
        bool valid = (y + di >= 1) && (y + di <= 56) && (xc + dj >= 1) && (xc + dj <= 56);
        if (valid) {
            const unsigned short* ap = xnh + (p + (di - 1) * 56 + (dj - 1)) * 128 + icb + q * 8;
            a0 = *(const uint4*)ap;
        }
        bv0 = *(const uint4*)(bg + it * 64);
        bv1 = *(const uint4*)(bg + it * 64 + 8);
    };

    // prologue: stage 0 into buffer 0
    issue(0);
    *(uint4*)(&As[0][aswo]) = a0;
    *(uint4*)(&Bs[0][bswo + 0]) = bv0;
    *(uint4*)(&Bs[0][bswo + 8]) = bv1;
    __syncthreads();

    #pragma unroll
    for (int it = 0; it < 18; it++) {
        const int cur = it & 1;
        if (it < 17) issue(it + 1);            // loads fly under MFMA below
        #pragma unroll
        for (int kk = 0; kk < 64; kk += 32) {
            bf16x8 af[2], bf[2];
            #pragma unroll
            for (int mt = 0; mt < 2; mt++)
                af[mt] = *(const bf16x8*)&As[cur][(wr * 32 + mt * 16 + lm) * LDP + kk + lq * 8];
            #pragma unroll
            for (int nt = 0; nt < 2; nt++)
                bf[nt] = *(const bf16x8*)&Bs[cur][(wc * 32 + nt * 16 + lm) * LDP + kk + lq * 8];
            #pragma unroll
            for (int mt = 0; mt < 2; mt++)
                #pragma unroll
                for (int nt = 0; nt < 2; nt++)
                    acc[mt][nt] = __builtin_amdgcn_mfma_f32_16x16x32_bf16(af[mt], bf[nt], acc[mt][nt], 0, 0, 0);
        }
        if (it < 17) {                         // write NEXT stage to other buffer;
            const int nxt = cur ^ 1;           // last reader of that buffer was iter
            *(uint4*)(&As[nxt][aswo]) = a0;    // it-1's MFMA, separated by barrier(it-1)
            *(uint4*)(&Bs[nxt][bswo + 0]) = bv0;
            *(uint4*)(&Bs[nxt][bswo + 8]) = bv1;
            __syncthreads();                   // single barrier per stage
        }
    }
    #pragma unroll
    for (int mt = 0; mt < 2; mt++) {
        int m = m0 + wr * 32 + mt * 16 + lq * 4;
        #pragma unroll
        for (int nt = 0; nt < 2; nt++) {
            int n = wc * 32 + nt * 16 + lm;
            float bb = bias[n];
            #pragma unroll
            for (int r = 0; r < 4; r++)
                h[(m + r) * 128 + n] = f2bf(fmaxf(acc[mt][nt][r] + bb, 0.f));
        }
    }
}

// ---- k_conv2f: conv2 (NHWC bf16 h, LDS fp32 weights) + theta epilogue, fused ----
// XCD-chunked: grid 1464 = 8 x 183 (6 idle).
__global__ __launch_bounds__(256) void k_conv2f(const unsigned short* __restrict__ h,
                                                const float* __restrict__ w1,
                                                const int* __restrict__ check,
                                                float* __restrict__ o_out,
                                                float* __restrict__ o_th,
                                                float* __restrict__ o_ax,
                                                float* __restrict__ o_ay,
                                                float* __restrict__ sxy) {
    __shared__ float wlds[6912];        // [r][ij*128+ic]
    __shared__ float red[16 * 6 * 17];  // [pt][r][c] stride-17
    __shared__ float vals[96];
    const int bid = (blockIdx.x & 7) * 183 + (blockIdx.x >> 3);   // chunked remap
    if (bid >= 1458) return;            // uniform early-out, before any barrier
    const int tid = threadIdx.x;
    for (int idx = tid; idx < 6912; idx += 256) {
        int r = idx / KDIM, k = idx - r * KDIM;
        int ij = k >> 7, ic = k & 127;
        wlds[idx] = w1[r * KDIM + ic * 9 + ij];
    }
    __syncthreads();
    const int pt = tid >> 4, c = tid & 15;
    const int p = bid * 16 + pt;
    int b = p / OPLANE; int rem = p - b * OPLANE; int oh = rem / 54; int ow = rem - oh * 54;
    const uint4* h4 = (const uint4*)h;          // 8 bf16 channels per uint4
    const float4* w4 = (const float4*)wlds;
    float acc[6] = {0.f, 0.f, 0.f, 0.f, 0.f, 0.f};
    const int base_sp = b * PLANE + oh * 56 + ow;
    #pragma unroll
    for (int i = 0; i < 3; i++) {
        #pragma unroll
        for (int j = 0; j < 3; j++) {
            int sp = base_sp + i * 56 + j;
            uint4 hu = h4[sp * 16 + c];         // ch c*8 .. c*8+7 (bf16 pairs)
            float f0 = bflo(hu.x), f1 = bfhi(hu.x);
            float f2 = bflo(hu.y), f3 = bfhi(hu.y);
            float f4 = bflo(hu.z), f5 = bfhi(hu.z);
            float f6 = bflo(hu.w), f7 = bfhi(hu.w);
            int ij = i * 3 + j;
            #pragma unroll
            for (int r = 0; r < 6; r++) {
                float4 wa = w4[r * 288 + ij * 32 + c * 2];
                float4 wb = w4[r * 288 + ij * 32 + c * 2 + 1];
                acc[r] += f0 * wa.x + f1 * wa.y + f2 * wa.z + f3 * wa.w
                        + f4 * wb.x + f5 * wb.y + f6 * wb.z + f7 * wb.w;
            }
        }
    }
    #pragma unroll
    for (int r = 0; r < 6; r++) red[(pt * 6 + r) * 17 + c] = acc[r];
    __syncthreads();
    if (tid < 96) {
        const float* rp = &red[tid * 17];
        float s = 0.f;
        #pragma unroll
        for (int e = 0; e < 16; e++) s += rp[e];
        vals[tid] = s;
    }
    __syncthreads();
    if (tid < 16) {
        int p2 = bid * 16 + tid;
        int b2 = p2 / OPLANE; int r2 = p2 - b2 * OPLANE; int oh2 = r2 / 54; int ow2 = r2 - oh2 * 54;
        float val[6];
        float s = 1.0f - (float)check[0];
        const float id6[6] = {1.f, 0.f, 0.f, 0.f, 1.f, 0.f};
        #pragma unroll
        for (int r = 0; r < 6; r++) val[r] = vals[tid * 6 + r] * s + id6[r];
        int n = (b2 * 54 + ow2) * 54 + oh2;
        #pragma unroll
        for (int r = 0; r < 6; r++) {
            o_out[((b2 * 6 + r) * 54 + oh2) * 54 + ow2] = val[r];
            o_th[n * 6 + r] = id6[r] - val[r];
        }
        const float bse[3] = {-2.f / 3.f, 0.f, 2.f / 3.f};
        #pragma unroll
        for (int i = 0; i < 3; i++)
            #pragma unroll
            for (int j = 0; j < 3; j++) {
                float gx = bse[j] * val[0] + bse[i] * val[1] + val[2];
                float gy = bse[j] * val[3] + bse[i] * val[4] + val[5];
                float ax = (gx + 1.f + (float)ow2) * (2.f / 55.f) - 1.f;
                float ay = (gy + 1.f + (float)oh2) * (2.f / 55.f) - 1.f;
                int ij = i * 3 + j;
                o_ax[n * 9 + ij] = ax;
                o_ay[n * 9 + ij] = ay;
                sxy[(n * 9 + ij) * 2 + 0] = (ax + 1.f) * 28.f - 0.5f;
                sxy[(n * 9 + ij) * 2 + 1] = (ay + 1.f) * 28.f - 0.5f;
            }
    }
}

// ---- k_sgemm: proven 64s x 128o + XCD chunked swizzle + cvt_pk pack ----
__global__ __launch_bounds__(256) void k_sgemm(const unsigned short* __restrict__ xnh,
                                               const unsigned short* __restrict__ Wt,
                                               const float* __restrict__ bias,
                                               const float* __restrict__ sxy,
                                               float* __restrict__ score) {
    __shared__ unsigned short Ss[64 * LDP];    // samples (A-tile, gathered)
    __shared__ unsigned short Ws[128 * LDP];   // o-rows
    const int i = blockIdx.x;
    const int xcd = i & 7, j = i >> 3;         // j in [0,92)
    const int pp = xcd * 46 + (j >> 1);        // 46 contiguous s-tiles per XCD
    const int m8 = j & 1;                      // o-half (pair member, same XCD)
    if (pp >= 365) return;                     // uniform per-block
    const int o0 = m8 * 128;
    const int s0 = pp * 64;
    const int tid = threadIdx.x;
    const int lane = tid & 63, wid = tid >> 6;
    const int wr = wid >> 1, wc = wid & 1;

    f32x4 acc[4][2];
    #pragma unroll
    for (int mt = 0; mt < 4; mt++)
        #pragma unroll
        for (int nt = 0; nt < 2; nt++) { acc[mt][nt][0]=0.f; acc[mt][nt][1]=0.f; acc[mt][nt][2]=0.f; acc[mt][nt][3]=0.f; }

    // gather assignment: row = sample (64), q = ic-sixteenth (4)
    const int row = tid >> 2, q = tid & 3;
    const int mp = min(s0 + row, NN - 1);           // score-linear sample id
    const int b = mp / OPLANE; const int rr = mp - b * OPLANE;
    const int ho = rr / 54, wo = rr - (rr / 54) * 54;
    const int n = (b * 54 + wo) * 54 + ho;          // theta-order id (sxy index)
    const int xbase = b * PLANE;
    unsigned short* ssw = &Ss[row * LDP + q * 16];
    // weight staging: wrow = o-row (128), wq = half (2), 4 uint4 per thread
    const int wrow = tid >> 1, wq = tid & 1;
    const unsigned short* wg = Wt + (o0 + wrow) * KDIM + wq * 32;
    unsigned short* wsw = &Ws[wrow * LDP + wq * 32];
    const int lm = lane & 15, lq = lane >> 4;

    // hoist all 9 sample coordinates out of the K-loop
    float2 sc[9];
    {
        const float* spp = sxy + n * 18;
        #pragma unroll
        for (int ij = 0; ij < 9; ij++) sc[ij] = *(const float2*)(spp + ij * 2);
    }

    int off0 = 0, off1 = 0, off2 = 0, off3 = 0;
    float wt0 = 0.f, wt1 = 0.f, wt2 = 0.f, wt3 = 0.f;
    auto mkoff = [&](int ij) {
        float sx = sc[ij].x, sy = sc[ij].y;
        float x0f = floorf(sx), y0f = floorf(sy);
        float wx = sx - x0f, wy = sy - y0f;
        int x0 = (int)x0f, y0 = (int)y0f;
        int x1 = x0 + 1, y1 = y0 + 1;
        float vx0 = (x0 >= 0 && x0 < 56) ? 1.f : 0.f;
        float vx1 = (x1 >= 0 && x1 < 56) ? 1.f : 0.f;
        float vy0 = (y0 >= 0 && y0 < 56) ? 1.f : 0.f;
        float vy1 = (y1 >= 0 && y1 < 56) ? 1.f : 0.f;
        int xc0 = min(max(x0, 0), 55), xc1 = min(max(x1, 0), 55);
        int yc0 = min(max(y0, 0), 55), yc1 = min(max(y1, 0), 55);
        off0 = (xbase + yc0 * 56 + xc0) << 7;
        off1 = (xbase + yc0 * 56 + xc1) << 7;
        off2 = (xbase + yc1 * 56 + xc0) << 7;
        off3 = (xbase + yc1 * 56 + xc1) << 7;
        wt0 = vy0 * vx0 * (1.f - wx) * (1.f - wy);
        wt1 = vy0 * vx1 * wx * (1.f - wy);
        wt2 = vy1 * vx0 * (1.f - wx) * wy;
        wt3 = vy1 * vx1 * wx * wy;
    };

    uint4 p0a, p0b, p1a, p1b, p2a, p2b, p3a, p3b;
    uint4 w0v, w1v, w2v, w3v;
    auto issue = [&](int it) {
        const int co = ((it & 1) << 6) + q * 16;
        p0a = *(const uint4*)(xnh + off0 + co);
        p0b = *(const uint4*)(xnh + off0 + co + 8);
        p1a = *(const uint4*)(xnh + off1 + co);
        p1b = *(const uint4*)(xnh + off1 + co + 8);
        p2a = *(const uint4*)(xnh + off2 + co);
        p2b = *(const uint4*)(xnh + off2 + co + 8);
        p3a = *(const uint4*)(xnh + off3 + co);
        p3b = *(const uint4*)(xnh + off3 + co + 8);
        w0v = *(const uint4*)(wg + it * 64);
        w1v = *(const uint4*)(wg + it * 64 + 8);
        w2v = *(const uint4*)(wg + it * 64 + 16);
        w3v = *(const uint4*)(wg + it * 64 + 24);
    };

    mkoff(0);
    issue(0);

    #pragma unroll
    for (int it = 0; it < 18; it++) {
        // blend 16 lanes (plain C, compiler-scheduled); pack via v_cvt_pk_bf16_f32
        unsigned dw[8];
        const unsigned* d0 = (const unsigned*)&p0a;
        const unsigned* d1 = (const unsigned*)&p1a;
        const unsigned* d2 = (const unsigned*)&p2a;
        const unsigned* d3 = (const unsigned*)&p3a;
        const unsigned* e0 = (const unsigned*)&p0b;
        const unsigned* e1 = (const unsigned*)&p1b;
        const unsigned* e2 = (const unsigned*)&p2b;
        const unsigned* e3 = (const unsigned*)&p3b;
        #pragma unroll
        for (int d = 0; d < 8; d++) {
            unsigned u0 = (d < 4) ? d0[d] : e0[d - 4];
            unsigned u1 = (d < 4) ? d1[d] : e1[d - 4];
            unsigned u2 = (d < 4) ? d2[d] : e2[d - 4];
            unsigned u3 = (d < 4) ? d3[d] : e3[d - 4];
            float lo = wt0 * bflo(u0) + wt1 * bflo(u1) + wt2 * bflo(u2) + wt3 * bflo(u3);
            float hi = wt0 * bfhi(u0) + wt1 * bfhi(u1) + wt2 * bfhi(u2) + wt3 * bfhi(u3);
            unsigned pk;
            asm("v_cvt_pk_bf16_f32 %0, %1, %2" : "=v"(pk) : "v"(lo), "v"(hi));
            dw[d] = pk;
        }
        __syncthreads();                      // prev MFMA reads of LDS done
        *(uint4*)(ssw + 0) = *(uint4*)&dw[0];
        *(uint4*)(ssw + 8) = *(uint4*)&dw[4];
        *(uint4*)(wsw + 0)  = w0v;
        *(uint4*)(wsw + 8)  = w1v;
        *(uint4*)(wsw + 16) = w2v;
        *(uint4*)(wsw + 24) = w3v;
        __syncthreads();
        if (it < 17) {                        // prefetch next stage
            if (((it + 1) & 1) == 0) mkoff((it + 1) >> 1);
            issue(it + 1);
        }
        #pragma unroll
        for (int kk = 0; kk < 64; kk += 32) {
            bf16x8 wf[4], sf[2];
            #pragma unroll
            for (int mt = 0; mt < 4; mt++)
                wf[mt] = *(const bf16x8*)&Ws[(wr * 64 + mt * 16 + lm) * LDP + kk + lq * 8];
            #pragma unroll
            for (int nt = 0; nt < 2; nt++)
                sf[nt] = *(const bf16x8*)&Ss[(wc * 32 + nt * 16 + lm) * LDP + kk + lq * 8];
            #pragma unroll
            for (int mt = 0; mt < 4; mt++)
                #pragma unroll
                for (int nt = 0; nt < 2; nt++)
                    acc[mt][nt] = __builtin_amdgcn_mfma_f32_16x16x32_bf16(wf[mt], sf[nt], acc[mt][nt], 0, 0, 0);
        }
    }
    #pragma unroll
    for (int mt = 0; mt < 4; mt++) {
        #pragma unroll
        for (int r = 0; r < 4; r++) {
            int o = o0 + wr * 64 + mt * 16 + lq * 4 + r;
            float bb = bias[o];
            #pragma unroll
            for (int nt = 0; nt < 2; nt++) {
                int s = s0 + wc * 32 + nt * 16 + lm;
                if (s < NN) {
                    int sb = s / OPLANE;
                    int soff = s - sb * OPLANE;
                    score[(sb * 256 + o) * OPLANE + soff] = acc[mt][nt][r] + bb;
                }
            }
        }
    }
}

extern "C" void kernel_launch(void* const* d_in, const int* in_sizes, int n_in,
                              void* d_out, int out_size, void* d_ws, size_t ws_size,
                              hipStream_t stream) {
    const float* x  = (const float*)d_in[0];
    const float* w0 = (const float*)d_in[1];
    const float* b0 = (const float*)d_in[2];
    const float* w1 = (const float*)d_in[3];
    const float* lw = (const float*)d_in[4];
    const float* lb = (const float*)d_in[5];
    const int* check = (const int*)d_in[6];

    float* out   = (float*)d_out;
    float* score = out;                    // 8*256*54*54 = 5,971,968
    float* o_th  = out + 5971968;          // 139,968
    float* o_out = out + 6111936;          // 139,968
    float* o_ax  = out + 6251904;          // 209,952
    float* o_ay  = out + 6461856;          // 209,952

    char* wsb = (char*)d_ws;
    unsigned short* h   = (unsigned short*)wsb;                  //   6,422,528 B (bf16)
    unsigned short* xnh = (unsigned short*)(wsb + 12845056);     //   6,422,528 B
    unsigned short* b1t = (unsigned short*)(wsb + 19267584);     //     294,912 B
    unsigned short* b2t = (unsigned short*)(wsb + 19562496);     //     589,824 B
    float* sxy = (float*)(wsb + 20152320);                       //   1,679,616 B -> 21.8 MB total

    k_pre<<<2176, 256, 0, stream>>>(x, w0, lw, xnh, b1t, b2t);
    k_gemm1<<<392, 512, 0, stream>>>(xnh, b1t, b0, h);
    k_conv2f<<<1464, 256, 0, stream>>>(h, w1, check, o_out, o_th, o_ax, o_ay, sxy);
    k_sgemm<<<736, 256, 0, stream>>>(xnh, b2t, lb, sxy, score);
}

// Round 14
// 154.098 us; speedup vs baseline: 1.0492x; 1.0399x over previous
//
#include <hip/hip_runtime.h>

typedef __attribute__((ext_vector_type(4))) float f32x4;
typedef __attribute__((ext_vector_type(8))) short bf16x8;

#define OPLANE 2916     // 54*54
#define NN 23328        // 8*54*54
#define KDIM 1152       // 128*9
#define PLANE 3136      // 56*56
#define LDP 72          // LDS row (shorts): 144B stride -> 2-way alias (free)
#define BS_LDP 1160     // conv2f B row (shorts): 2320B stride -> ~2-way on frag reads

__device__ __forceinline__ unsigned short f2bf(float f) {
    unsigned u = __builtin_bit_cast(unsigned, f);
    u += 0x7fffu + ((u >> 16) & 1u);
    return (unsigned short)(u >> 16);
}
__device__ __forceinline__ float bflo(unsigned u) {   // low bf16 of dword -> f32
    return __builtin_bit_cast(float, u << 16);
}
__device__ __forceinline__ float bfhi(unsigned u) {   // high bf16 of dword -> f32
    return __builtin_bit_cast(float, u & 0xffff0000u);
}

// ---- k_pre: fused {w0/lw->bf16 K-permute} + {w1->bf16 padded} + {x NCHW -> NHWC bf16} ----
// blocks [0,1728): w0/lw prep; [1728,1800): w1 prep (b3t, 16x1152, rows 6..15 zero);
// [1800,2248): nhwc transpose.
__global__ __launch_bounds__(256) void k_pre(const float* __restrict__ x,
                                             const float* __restrict__ w0,
                                             const float* __restrict__ lw,
                                             const float* __restrict__ w1,
                                             unsigned short* __restrict__ xnh,
                                             unsigned short* __restrict__ b1t,
                                             unsigned short* __restrict__ b2t,
                                             unsigned short* __restrict__ b3t) {
    __shared__ unsigned short lds[56 * 132];
    if (blockIdx.x < 1728) {
        int idx = blockIdx.x * 256 + threadIdx.x;   // 442368 = 147456 + 294912
        if (idx < 147456) {
            int r = idx / KDIM, k = idx - r * KDIM;
            int ij = k >> 7, ic = k & 127;
            b1t[idx] = f2bf(w0[r * KDIM + ic * 9 + ij]);
        } else {
            int j = idx - 147456;
            int r = j / KDIM, k = j - r * KDIM;
            int ij = k >> 7, ic = k & 127;
            b2t[j] = f2bf(lw[r * KDIM + ic * 9 + ij]);
        }
    } else if (blockIdx.x < 1800) {
        int idx = (blockIdx.x - 1728) * 256 + threadIdx.x;  // < 18432 = 16*1152
        int r = idx / KDIM, k = idx - r * KDIM;
        int ij = k >> 7, ic = k & 127;
        b3t[idx] = (r < 6) ? f2bf(w1[r * KDIM + ic * 9 + ij]) : (unsigned short)0;
    } else {
        const int bid = blockIdx.x - 1800;
        const int y = bid % 56, b = bid / 56, tid = threadIdx.x;
        for (int i = tid; i < 7168; i += 256) {
            int ic = i / 56, xc = i - ic * 56;
            lds[xc * 132 + ic] = f2bf(x[(b * 128 + ic) * PLANE + y * 56 + xc]);
        }
        __syncthreads();
        for (int i = tid; i < 7168; i += 256) {
            int xc = i >> 7, ic = i & 127;
            xnh[(b * PLANE + y * 56 + xc) * 128 + ic] = lds[xc * 132 + ic];
        }
    }
}

// ---- gemm1 (fused im2col): h = relu(im2col(xnh) * b1t^T + b0), h stored BF16 ----
// BK=64, double-buffered LDS (single barrier/stage). XCD-chunked m-tiles.
__global__ __launch_bounds__(512) void k_gemm1(const unsigned short* __restrict__ xnh,
                                               const unsigned short* __restrict__ Bt,
                                               const float* __restrict__ bias,
                                               unsigned short* __restrict__ h) {
    __shared__ unsigned short As[2][64 * LDP];
    __shared__ unsigned short Bs[2][128 * LDP];
    const int tid = threadIdx.x;
    const int lane = tid & 63, wid = tid >> 6;   // 8 waves
    const int wr = wid >> 2, wc = wid & 3;       // 2 m-halves x 4 n-quarters
    const int mt_id = (blockIdx.x & 7) * 49 + (blockIdx.x >> 3);  // chunked remap
    const int m0 = mt_id * 64;

    f32x4 acc[2][2];
    #pragma unroll
    for (int mt = 0; mt < 2; mt++)
        #pragma unroll
        for (int nt = 0; nt < 2; nt++) { acc[mt][nt][0]=0.f; acc[mt][nt][1]=0.f; acc[mt][nt][2]=0.f; acc[mt][nt][3]=0.f; }

    const int row = tid >> 3, q = tid & 7;
    const int p = m0 + row;
    const int b = p / PLANE; int rem = p - b * PLANE;
    const int y = rem / 56; const int xc = rem - y * 56;
    const int aswo = row * LDP + q * 8;
    const int brow = tid >> 2, bq = tid & 3;
    const unsigned short* bg = Bt + brow * KDIM + bq * 16;
    const int bswo = brow * LDP + bq * 16;
    const int lm = lane & 15, lq = lane >> 4;

    uint4 a0, bv0, bv1;
    auto issue = [&](int it) {
        const int ij = it >> 1;
        const int di = ij / 3, dj = ij - di * 3;
        const int icb = (it & 1) << 6;
        a0 = make_uint4(0u,0u,0u,0u);
        bool valid = (y + di >= 1) && (y + di <= 56) && (xc + dj >= 1) && (xc + dj <= 56);
        if (valid) {
            const unsigned short* ap = xnh + (p + (di - 1) * 56 + (dj - 1)) * 128 + icb + q * 8;
            a0 = *(const uint4*)ap;
        }
        bv0 = *(const uint4*)(bg + it * 64);
        bv1 = *(const uint4*)(bg + it * 64 + 8);
    };

    issue(0);
    *(uint4*)(&As[0][aswo]) = a0;
    *(uint4*)(&Bs[0][bswo + 0]) = bv0;
    *(uint4*)(&Bs[0][bswo + 8]) = bv1;
    __syncthreads();

    #pragma unroll
    for (int it = 0; it < 18; it++) {
        const int cur = it & 1;
        if (it < 17) issue(it + 1);
        #pragma unroll
        for (int kk = 0; kk < 64; kk += 32) {
            bf16x8 af[2], bf[2];
            #pragma unroll
            for (int mt = 0; mt < 2; mt++)
                af[mt] = *(const bf16x8*)&As[cur][(wr * 32 + mt * 16 + lm) * LDP + kk + lq * 8];
            #pragma unroll
            for (int nt = 0; nt < 2; nt++)
                bf[nt] = *(const bf16x8*)&Bs[cur][(wc * 32 + nt * 16 + lm) * LDP + kk + lq * 8];
            #pragma unroll
            for (int mt = 0; mt < 2; mt++)
                #pragma unroll
                for (int nt = 0; nt < 2; nt++)
                    acc[mt][nt] = __builtin_amdgcn_mfma_f32_16x16x32_bf16(af[mt], bf[nt], acc[mt][nt], 0, 0, 0);
        }
        if (it < 17) {
            const int nxt = cur ^ 1;
            *(uint4*)(&As[nxt][aswo]) = a0;
            *(uint4*)(&Bs[nxt][bswo + 0]) = bv0;
            *(uint4*)(&Bs[nxt][bswo + 8]) = bv1;
            __syncthreads();
        }
    }
    #pragma unroll
    for (int mt = 0; mt < 2; mt++) {
        int m = m0 + wr * 32 + mt * 16 + lq * 4;
        #pragma unroll
        for (int nt = 0; nt < 2; nt++) {
            int n = wc * 32 + nt * 16 + lm;
            float bb = bias[n];
            #pragma unroll
            for (int r = 0; r < 4; r++)
                h[(m + r) * 128 + n] = f2bf(fmaxf(acc[mt][nt][r] + bb, 0.f));
        }
    }
}

// ---- k_conv2f (MFMA): C2 = im2col(h) x b3t^T (N=16, 6 used) + theta epilogue ----
// B (16x1152 bf16) loaded into LDS once; main loop stages A only (valid conv, no
// bounds checks). 64 samples/block, 4 waves x 16 rows, 18 stages x 2 MFMA.
// Grid 368 = 8 x 46 XCD-chunked (each XCD ~ one batch image of h).
__global__ __launch_bounds__(256) void k_conv2f(const unsigned short* __restrict__ h,
                                                const unsigned short* __restrict__ Wt2,
                                                const int* __restrict__ check,
                                                float* __restrict__ o_out,
                                                float* __restrict__ o_th,
                                                float* __restrict__ o_ax,
                                                float* __restrict__ o_ay,
                                                float* __restrict__ sxy) {
    __shared__ unsigned short Bs[16 * BS_LDP];   // 37.1 KB
    __shared__ unsigned short As[64 * LDP];      //  9.2 KB
    __shared__ float vals[64 * 6];
    const int bid = (blockIdx.x & 7) * 46 + (blockIdx.x >> 3);
    if (bid >= 365) return;                      // uniform per-block
    const int tid = threadIdx.x;
    const int lane = tid & 63, wid = tid >> 6;
    const int lm = lane & 15, lq = lane >> 4;
    const int m0 = bid * 64;

    // load B once: thread t -> row t>>4, 72 shorts at (t&15)*72 (9 uint4, 16B-aligned)
    {
        const int r = tid >> 4, kb = (tid & 15) * 72;
        const unsigned short* src = Wt2 + r * KDIM + kb;
        unsigned short* dst = &Bs[r * BS_LDP + kb];
        #pragma unroll
        for (int jj = 0; jj < 9; jj++)
            *(uint4*)(dst + jj * 8) = *(const uint4*)(src + jj * 8);
    }

    // A staging: row = sample (64), q = 16-short chunk (4)
    const int row = tid >> 2, q = tid & 3;
    const int p = min(m0 + row, NN - 1);
    const int b = p / OPLANE; const int rr = p - b * OPLANE;
    const int oh = rr / 54, ow = rr - oh * 54;
    const int hbase = b * PLANE + oh * 56 + ow;  // valid conv: window always in-bounds
    unsigned short* asw = &As[row * LDP + q * 16];

    f32x4 acc; acc[0] = 0.f; acc[1] = 0.f; acc[2] = 0.f; acc[3] = 0.f;

    uint4 a0, a1;
    auto issue = [&](int it) {
        const int ij = it >> 1;
        const int di = ij / 3, dj = ij - di * 3;
        const int icb = (it & 1) << 6;
        const unsigned short* ap = h + (hbase + di * 56 + dj) * 128 + icb + q * 16;
        a0 = *(const uint4*)ap;
        a1 = *(const uint4*)(ap + 8);
    };
    issue(0);

    #pragma unroll
    for (int it = 0; it < 18; it++) {
        __syncthreads();                 // prev MFMA done reading As (it=0: Bs ready)
        *(uint4*)(asw + 0) = a0;
        *(uint4*)(asw + 8) = a1;
        __syncthreads();
        if (it < 17) issue(it + 1);
        #pragma unroll
        for (int kk = 0; kk < 64; kk += 32) {
            bf16x8 af = *(const bf16x8*)&As[(wid * 16 + lm) * LDP + kk + lq * 8];
            bf16x8 bf = *(const bf16x8*)&Bs[lm * BS_LDP + it * 64 + kk + lq * 8];
            acc = __builtin_amdgcn_mfma_f32_16x16x32_bf16(af, bf, acc, 0, 0, 0);
        }
    }

    // scatter acc -> vals[sample][ch] (ch = lm < 6)
    if (lm < 6) {
        #pragma unroll
        for (int r4 = 0; r4 < 4; r4++)
            vals[(wid * 16 + lq * 4 + r4) * 6 + lm] = acc[r4];
    }
    __syncthreads();

    if (tid < 64) {
        int p2 = m0 + tid;
        if (p2 < NN) {
            int b2 = p2 / OPLANE; int r2 = p2 - b2 * OPLANE;
            int oh2 = r2 / 54; int ow2 = r2 - oh2 * 54;
            float val[6];
            float s = 1.0f - (float)check[0];
            const float id6[6] = {1.f, 0.f, 0.f, 0.f, 1.f, 0.f};
            #pragma unroll
            for (int r = 0; r < 6; r++) val[r] = vals[tid * 6 + r] * s + id6[r];
            int n = (b2 * 54 + ow2) * 54 + oh2;
            #pragma unroll
            for (int r = 0; r < 6; r++) {
                o_out[((b2 * 6 + r) * 54 + oh2) * 54 + ow2] = val[r];
                o_th[n * 6 + r] = id6[r] - val[r];
            }
            const float bse[3] = {-2.f / 3.f, 0.f, 2.f / 3.f};
            #pragma unroll
            for (int i = 0; i < 3; i++)
                #pragma unroll
                for (int j = 0; j < 3; j++) {
                    float gx = bse[j] * val[0] + bse[i] * val[1] + val[2];
                    float gy = bse[j] * val[3] + bse[i] * val[4] + val[5];
                    float ax = (gx + 1.f + (float)ow2) * (2.f / 55.f) - 1.f;
                    float ay = (gy + 1.f + (float)oh2) * (2.f / 55.f) - 1.f;
                    int ij = i * 3 + j;
                    o_ax[n * 9 + ij] = ax;
                    o_ay[n * 9 + ij] = ay;
                    sxy[(n * 9 + ij) * 2 + 0] = (ax + 1.f) * 28.f - 0.5f;
                    sxy[(n * 9 + ij) * 2 + 1] = (ay + 1.f) * 28.f - 0.5f;
                }
        }
    }
}

// ---- k_sgemm: proven 64s x 128o + XCD chunked swizzle + cvt_pk pack ----
__global__ __launch_bounds__(256) void k_sgemm(const unsigned short* __restrict__ xnh,
                                               const unsigned short* __restrict__ Wt,
                                               const float* __restrict__ bias,
                                               const float* __restrict__ sxy,
                                               float* __restrict__ score) {
    __shared__ unsigned short Ss[64 * LDP];    // samples (A-tile, gathered)
    __shared__ unsigned short Ws[128 * LDP];   // o-rows
    const int i = blockIdx.x;
    const int xcd = i & 7, j = i >> 3;         // j in [0,92)
    const int pp = xcd * 46 + (j >> 1);        // 46 contiguous s-tiles per XCD
    const int m8 = j & 1;                      // o-half (pair member, same XCD)
    if (pp >= 365) return;                     // uniform per-block
    const int o0 = m8 * 128;
    const int s0 = pp * 64;
    const int tid = threadIdx.x;
    const int lane = tid & 63, wid = tid >> 6;
    const int wr = wid >> 1, wc = wid & 1;

    f32x4 acc[4][2];
    #pragma unroll
    for (int mt = 0; mt < 4; mt++)
        #pragma unroll
        for (int nt = 0; nt < 2; nt++) { acc[mt][nt][0]=0.f; acc[mt][nt][1]=0.f; acc[mt][nt][2]=0.f; acc[mt][nt][3]=0.f; }

    const int row = tid >> 2, q = tid & 3;
    const int mp = min(s0 + row, NN - 1);           // score-linear sample id
    const int b = mp / OPLANE; const int rr = mp - b * OPLANE;
    const int ho = rr / 54, wo = rr - (rr / 54) * 54;
    const int n = (b * 54 + wo) * 54 + ho;          // theta-order id (sxy index)
    const int xbase = b * PLANE;
    unsigned short* ssw = &Ss[row * LDP + q * 16];
    const int wrow = tid >> 1, wq = tid & 1;
    const unsigned short* wg = Wt + (o0 + wrow) * KDIM + wq * 32;
    unsigned short* wsw = &Ws[wrow * LDP + wq * 32];
    const int lm = lane & 15, lq = lane >> 4;

    float2 sc[9];
    {
        const float* spp = sxy + n * 18;
        #pragma unroll
        for (int ij = 0; ij < 9; ij++) sc[ij] = *(const float2*)(spp + ij * 2);
    }

    int off0 = 0, off1 = 0, off2 = 0, off3 = 0;
    float wt0 = 0.f, wt1 = 0.f, wt2 = 0.f, wt3 = 0.f;
    auto mkoff = [&](int ij) {
        float sx = sc[ij].x, sy = sc[ij].y;
        float x0f = floorf(sx), y0f = floorf(sy);
        float wx = sx - x0f, wy = sy - y0f;
        int x0 = (int)x0f, y0 = (int)y0f;
        int x1 = x0 + 1, y1 = y0 + 1;
        float vx0 = (x0 >= 0 && x0 < 56) ? 1.f : 0.f;
        float vx1 = (x1 >= 0 && x1 < 56) ? 1.f : 0.f;
        float vy0 = (y0 >= 0 && y0 < 56) ? 1.f : 0.f;
        float vy1 = (y1 >= 0 && y1 < 56) ? 1.f : 0.f;
        int xc0 = min(max(x0, 0), 55), xc1 = min(max(x1, 0), 55);
        int yc0 = min(max(y0, 0), 55), yc1 = min(max(y1, 0), 55);
        off0 = (xbase + yc0 * 56 + xc0) << 7;
        off1 = (xbase + yc0 * 56 + xc1) << 7;
        off2 = (xbase + yc1 * 56 + xc0) << 7;
        off3 = (xbase + yc1 * 56 + xc1) << 7;
        wt0 = vy0 * vx0 * (1.f - wx) * (1.f - wy);
        wt1 = vy0 * vx1 * wx * (1.f - wy);
        wt2 = vy1 * vx0 * (1.f - wx) * wy;
        wt3 = vy1 * vx1 * wx * wy;
    };

    uint4 p0a, p0b, p1a, p1b, p2a, p2b, p3a, p3b;
    uint4 w0v, w1v, w2v, w3v;
    auto issue = [&](int it) {
        const int co = ((it & 1) << 6) + q * 16;
        p0a = *(const uint4*)(xnh + off0 + co);
        p0b = *(const uint4*)(xnh + off0 + co + 8);
        p1a = *(const uint4*)(xnh + off1 + co);
        p1b = *(const uint4*)(xnh + off1 + co + 8);
        p2a = *(const uint4*)(xnh + off2 + co);
        p2b = *(const uint4*)(xnh + off2 + co + 8);
        p3a = *(const uint4*)(xnh + off3 + co);
        p3b = *(const uint4*)(xnh + off3 + co + 8);
        w0v = *(const uint4*)(wg + it * 64);
        w1v = *(const uint4*)(wg + it * 64 + 8);
        w2v = *(const uint4*)(wg + it * 64 + 16);
        w3v = *(const uint4*)(wg + it * 64 + 24);
    };

    mkoff(0);
    issue(0);

    #pragma unroll
    for (int it = 0; it < 18; it++) {
        unsigned dw[8];
        const unsigned* d0 = (const unsigned*)&p0a;
        const unsigned* d1 = (const unsigned*)&p1a;
        const unsigned* d2 = (const unsigned*)&p2a;
        const unsigned* d3 = (const unsigned*)&p3a;
        const unsigned* e0 = (const unsigned*)&p0b;
        const unsigned* e1 = (const unsigned*)&p1b;
        const unsigned* e2 = (const unsigned*)&p2b;
        const unsigned* e3 = (const unsigned*)&p3b;
        #pragma unroll
        for (int d = 0; d < 8; d++) {
            unsigned u0 = (d < 4) ? d0[d] : e0[d - 4];
            unsigned u1 = (d < 4) ? d1[d] : e1[d - 4];
            unsigned u2 = (d < 4) ? d2[d] : e2[d - 4];
            unsigned u3 = (d < 4) ? d3[d] : e3[d - 4];
            float lo = wt0 * bflo(u0) + wt1 * bflo(u1) + wt2 * bflo(u2) + wt3 * bflo(u3);
            float hi = wt0 * bfhi(u0) + wt1 * bfhi(u1) + wt2 * bfhi(u2) + wt3 * bfhi(u3);
            unsigned pk;
            asm("v_cvt_pk_bf16_f32 %0, %1, %2" : "=v"(pk) : "v"(lo), "v"(hi));
            dw[d] = pk;
        }
        __syncthreads();                      // prev MFMA reads of LDS done
        *(uint4*)(ssw + 0) = *(uint4*)&dw[0];
        *(uint4*)(ssw + 8) = *(uint4*)&dw[4];
        *(uint4*)(wsw + 0)  = w0v;
        *(uint4*)(wsw + 8)  = w1v;
        *(uint4*)(wsw + 16) = w2v;
        *(uint4*)(wsw + 24) = w3v;
        __syncthreads();
        if (it < 17) {                        // prefetch next stage
            if (((it + 1) & 1) == 0) mkoff((it + 1) >> 1);
            issue(it + 1);
        }
        #pragma unroll
        for (int kk = 0; kk < 64; kk += 32) {
            bf16x8 wf[4], sf[2];
            #pragma unroll
            for (int mt = 0; mt < 4; mt++)
                wf[mt] = *(const bf16x8*)&Ws[(wr * 64 + mt * 16 + lm) * LDP + kk + lq * 8];
            #pragma unroll
            for (int nt = 0; nt < 2; nt++)
                sf[nt] = *(const bf16x8*)&Ss[(wc * 32 + nt * 16 + lm) * LDP + kk + lq * 8];
            #pragma unroll
            for (int mt = 0; mt < 4; mt++)
                #pragma unroll
                for (int nt = 0; nt < 2; nt++)
                    acc[mt][nt] = __builtin_amdgcn_mfma_f32_16x16x32_bf16(wf[mt], sf[nt], acc[mt][nt], 0, 0, 0);
        }
    }
    #pragma unroll
    for (int mt = 0; mt < 4; mt++) {
        #pragma unroll
        for (int r = 0; r < 4; r++) {
            int o = o0 + wr * 64 + mt * 16 + lq * 4 + r;
            float bb = bias[o];
            #pragma unroll
            for (int nt = 0; nt < 2; nt++) {
                int s = s0 + wc * 32 + nt * 16 + lm;
                if (s < NN) {
                    int sb = s / OPLANE;
                    int soff = s - sb * OPLANE;
                    score[(sb * 256 + o) * OPLANE + soff] = acc[mt][nt][r] + bb;
                }
            }
        }
    }
}

extern "C" void kernel_launch(void* const* d_in, const int* in_sizes, int n_in,
                              void* d_out, int out_size, void* d_ws, size_t ws_size,
                              hipStream_t stream) {
    const float* x  = (const float*)d_in[0];
    const float* w0 = (const float*)d_in[1];
    const float* b0 = (const float*)d_in[2];
    const float* w1 = (const float*)d_in[3];
    const float* lw = (const float*)d_in[4];
    const float* lb = (const float*)d_in[5];
    const int* check = (const int*)d_in[6];

    float* out   = (float*)d_out;
    float* score = out;                    // 8*256*54*54 = 5,971,968
    float* o_th  = out + 5971968;          // 139,968
    float* o_out = out + 6111936;          // 139,968
    float* o_ax  = out + 6251904;          // 209,952
    float* o_ay  = out + 6461856;          // 209,952

    char* wsb = (char*)d_ws;
    unsigned short* h   = (unsigned short*)wsb;                  //   6,422,528 B (bf16)
    unsigned short* b3t = (unsigned short*)(wsb + 6422528);      //      36,864 B (w1 bf16, 16 rows)
    unsigned short* xnh = (unsigned short*)(wsb + 12845056);     //   6,422,528 B
    unsigned short* b1t = (unsigned short*)(wsb + 19267584);     //     294,912 B
    unsigned short* b2t = (unsigned short*)(wsb + 19562496);     //     589,824 B
    float* sxy = (float*)(wsb + 20152320);                       //   1,679,616 B -> 21.8 MB total

    k_pre<<<2248, 256, 0, stream>>>(x, w0, lw, w1, xnh, b1t, b2t, b3t);
    k_gemm1<<<392, 512, 0, stream>>>(xnh, b1t, b0, h);
    k_conv2f<<<368, 256, 0, stream>>>(h, b3t, check, o_out, o_th, o_ax, o_ay, sxy);
    k_sgemm<<<736, 256, 0, stream>>>(xnh, b2t, lb, sxy, score);
}